// Round 1
// baseline (254.476 us; speedup 1.0000x reference)
//
#include <hip/hip_runtime.h>
#include <math.h>

#define B_ 8
#define T_ 100
#define S_ 400
#define H_ 256
#define BT_ (B_ * T_)
#define MAXL 30.0f

#define CTX_OFF 0
#define AF_OFF (BT_ * H_)
#define LOSS_OFF (BT_ * H_ + BT_ * S_)

// ws layout (floats)
#define WH_OFF 0
#define WS_OFF (B_ * S_ * H_)            // 819200
#define ACOV_OFF (WS_OFF + BT_ * H_)     // 1024000; size BT_*S_ = 320000

__device__ __forceinline__ float fast_tanh(float x) {
    // 1 - 2/(e^{2x}+1): saturates correctly for |x| large, ~1e-6 abs err
    float e = __expf(2.0f * x);
    return 1.0f - 2.0f * __builtin_amdgcn_rcpf(e + 1.0f);
}

__device__ __forceinline__ float wave_sum(float p) {
#pragma unroll
    for (int off = 32; off; off >>= 1) p += __shfl_xor(p, off, 64);
    return p;
}

__device__ __forceinline__ float wave_max(float p) {
#pragma unroll
    for (int off = 32; off; off >>= 1) p = fmaxf(p, __shfl_xor(p, off, 64));
    return p;
}

// ---------------- K1: Wh = enc @ W_h, Ws = dec @ W_s (row-block GEMM) --------
#define ROWS 16
__global__ __launch_bounds__(256) void k_gemm(
    const float* __restrict__ dec, const float* __restrict__ enc,
    const float* __restrict__ W_h, const float* __restrict__ W_s,
    float* __restrict__ Wh, float* __restrict__ Ws) {
    __shared__ float in_t[H_][ROWS];  // transposed: in_t[h][r]
    const int tid = threadIdx.x;
    const int blk = blockIdx.x;
    const int NB_ENC = (B_ * S_) / ROWS;  // 200

    const float* in;
    const float* W;
    float* out;
    int r0;
    if (blk < NB_ENC) {
        in = enc; W = W_h; out = Wh; r0 = blk * ROWS;
    } else {
        in = dec; W = W_s; out = Ws; r0 = (blk - NB_ENC) * ROWS;
    }

#pragma unroll
    for (int r = 0; r < ROWS; ++r)
        in_t[tid][r] = in[(size_t)(r0 + r) * H_ + tid];
    __syncthreads();

    float acc[ROWS];
#pragma unroll
    for (int r = 0; r < ROWS; ++r) acc[r] = 0.f;

    const float* Wp = W + tid;
    for (int h = 0; h < H_; ++h) {
        float w = Wp[(size_t)h * H_];
        const float4* ip = reinterpret_cast<const float4*>(&in_t[h][0]);
        float4 i0 = ip[0], i1 = ip[1], i2 = ip[2], i3 = ip[3];
        acc[0] += i0.x * w;  acc[1] += i0.y * w;  acc[2] += i0.z * w;  acc[3] += i0.w * w;
        acc[4] += i1.x * w;  acc[5] += i1.y * w;  acc[6] += i1.z * w;  acc[7] += i1.w * w;
        acc[8] += i2.x * w;  acc[9] += i2.y * w;  acc[10] += i2.z * w; acc[11] += i2.w * w;
        acc[12] += i3.x * w; acc[13] += i3.y * w; acc[14] += i3.z * w; acc[15] += i3.w * w;
    }
#pragma unroll
    for (int r = 0; r < ROWS; ++r)
        out[(size_t)(r0 + r) * H_ + tid] = acc[r];
}

// ---------------- K2: prelim logits + softmax -> A_prelim --------------------
__global__ __launch_bounds__(256) void k_prelim(
    const float* __restrict__ Wh, const float* __restrict__ Ws,
    const float* __restrict__ v, const float* __restrict__ b_attn,
    const unsigned char* __restrict__ mask,
    float* __restrict__ A) {
    __shared__ float e_lds[S_];
    __shared__ float red[8];
    const int bt = blockIdx.x;
    const int b = bt / T_;
    const int tid = threadIdx.x;
    const int lane = tid & 63;
    const int wid = tid >> 6;

    float4 base = *reinterpret_cast<const float4*>(Ws + (size_t)bt * H_ + lane * 4);
    const float4 bav = *reinterpret_cast<const float4*>(b_attn + lane * 4);
    base.x += bav.x; base.y += bav.y; base.z += bav.z; base.w += bav.w;
    const float4 vv = *reinterpret_cast<const float4*>(v + lane * 4);

    const float* WhB = Wh + (size_t)b * S_ * H_;
    const unsigned char* mb = mask + (size_t)b * S_;

    for (int s = wid; s < S_; s += 4) {
        float4 wh = *reinterpret_cast<const float4*>(WhB + (size_t)s * H_ + lane * 4);
        float p = fast_tanh(wh.x + base.x) * vv.x;
        p += fast_tanh(wh.y + base.y) * vv.y;
        p += fast_tanh(wh.z + base.z) * vv.z;
        p += fast_tanh(wh.w + base.w) * vv.w;
        p = wave_sum(p);
        if (lane == 0) {
            float e = fminf(fmaxf(p, -MAXL), MAXL);
            if (mb[s]) e = -INFINITY;
            e_lds[s] = e;
        }
    }
    __syncthreads();

    // softmax over S_
    float mx = -INFINITY;
    for (int s = tid; s < S_; s += 256) mx = fmaxf(mx, e_lds[s]);
    mx = wave_max(mx);
    if (lane == 0) red[wid] = mx;
    __syncthreads();
    mx = fmaxf(fmaxf(red[0], red[1]), fmaxf(red[2], red[3]));

    float sum = 0.f;
    for (int s = tid; s < S_; s += 256) {
        float p = __expf(e_lds[s] - mx);
        e_lds[s] = p;
        sum += p;
    }
    sum = wave_sum(sum);
    if (lane == 0) red[4 + wid] = sum;
    __syncthreads();
    sum = (red[4] + red[5]) + (red[6] + red[7]);
    float inv = __builtin_amdgcn_rcpf(sum);

    float* Ar = A + (size_t)bt * S_;
    for (int s = tid; s < S_; s += 256) Ar[s] = e_lds[s] * inv;
}

// ---------------- K3: in-place shifted cumsum over t; zero loss --------------
__global__ __launch_bounds__(256) void k_cumsum(float* __restrict__ A,
                                                float* __restrict__ out) {
    const int idx = blockIdx.x * 256 + threadIdx.x;  // b*S + s
    if (idx == 0) out[LOSS_OFF] = 0.f;
    if (idx >= B_ * S_) return;
    const int b = idx / S_;
    const int s = idx - b * S_;
    float* col = A + (size_t)b * T_ * S_ + s;
    float run = 0.f;
#pragma unroll 4
    for (int t = 0; t < T_; ++t) {
        float a = col[(size_t)t * S_];
        col[(size_t)t * S_] = run;  // cov_shifted
        run += a;
    }
}

// ---------------- K4: final logits + softmax + context + loss ----------------
__global__ __launch_bounds__(256) void k_final(
    const float* __restrict__ Wh, const float* __restrict__ Ws,
    const float* __restrict__ v, const float* __restrict__ b_attn,
    const float* __restrict__ w_c, const float* __restrict__ cov,
    const unsigned char* __restrict__ mask,
    const float* __restrict__ enc,
    float* __restrict__ out) {
    __shared__ float e_lds[S_];
    __shared__ float cov_lds[S_];
    __shared__ float red[8];
    const int bt = blockIdx.x;
    const int b = bt / T_;
    const int tid = threadIdx.x;
    const int lane = tid & 63;
    const int wid = tid >> 6;

    float4 base = *reinterpret_cast<const float4*>(Ws + (size_t)bt * H_ + lane * 4);
    const float4 bav = *reinterpret_cast<const float4*>(b_attn + lane * 4);
    base.x += bav.x; base.y += bav.y; base.z += bav.z; base.w += bav.w;
    const float4 vv = *reinterpret_cast<const float4*>(v + lane * 4);
    const float4 wcv = *reinterpret_cast<const float4*>(w_c + lane * 4);

    const float* covR = cov + (size_t)bt * S_;
    for (int s = tid; s < S_; s += 256) cov_lds[s] = covR[s];
    __syncthreads();

    const float* WhB = Wh + (size_t)b * S_ * H_;
    const unsigned char* mb = mask + (size_t)b * S_;

    for (int s = wid; s < S_; s += 4) {
        const float c = cov_lds[s];
        float4 wh = *reinterpret_cast<const float4*>(WhB + (size_t)s * H_ + lane * 4);
        float p = fast_tanh(wh.x + base.x + c * wcv.x) * vv.x;
        p += fast_tanh(wh.y + base.y + c * wcv.y) * vv.y;
        p += fast_tanh(wh.z + base.z + c * wcv.z) * vv.z;
        p += fast_tanh(wh.w + base.w + c * wcv.w) * vv.w;
        p = wave_sum(p);
        if (lane == 0) {
            float e = fminf(fmaxf(p, -MAXL), MAXL);
            if (mb[s]) e = -INFINITY;
            e_lds[s] = e;
        }
    }
    __syncthreads();

    float mx = -INFINITY;
    for (int s = tid; s < S_; s += 256) mx = fmaxf(mx, e_lds[s]);
    mx = wave_max(mx);
    if (lane == 0) red[wid] = mx;
    __syncthreads();
    mx = fmaxf(fmaxf(red[0], red[1]), fmaxf(red[2], red[3]));

    float sum = 0.f;
    for (int s = tid; s < S_; s += 256) {
        float p = __expf(e_lds[s] - mx);
        e_lds[s] = p;
        sum += p;
    }
    sum = wave_sum(sum);
    if (lane == 0) red[4 + wid] = sum;
    __syncthreads();
    sum = (red[4] + red[5]) + (red[6] + red[7]);
    const float inv = __builtin_amdgcn_rcpf(sum);

    float* Ar = out + AF_OFF + (size_t)bt * S_;
    for (int s = tid; s < S_; s += 256) {
        float a = e_lds[s] * inv;
        e_lds[s] = a;
        Ar[s] = a;
    }
    __syncthreads();

    // context[b,t,h] = sum_s A[s] * enc[b,s,h]; thread = h
    const float* eb = enc + (size_t)b * S_ * H_ + tid;
    float cacc = 0.f;
#pragma unroll 8
    for (int s = 0; s < S_; ++s) cacc += e_lds[s] * eb[(size_t)s * H_];
    out[(size_t)bt * H_ + tid] = cacc;

    // cov loss partial
    float lp = 0.f;
    for (int s = tid; s < S_; s += 256) lp += fminf(e_lds[s], cov_lds[s]);
    lp = wave_sum(lp);
    if (lane == 0) red[wid] = lp;
    __syncthreads();
    if (tid == 0) {
        float tot = (red[0] + red[1]) + (red[2] + red[3]);
        atomicAdd(out + LOSS_OFF, tot * (1.0f / (B_ * T_)));
    }
}

extern "C" void kernel_launch(void* const* d_in, const int* in_sizes, int n_in,
                              void* d_out, int out_size, void* d_ws, size_t ws_size,
                              hipStream_t stream) {
    const float* dec = (const float*)d_in[0];
    const float* enc = (const float*)d_in[1];
    const unsigned char* mask = (const unsigned char*)d_in[2];
    const float* W_h = (const float*)d_in[3];
    const float* W_s = (const float*)d_in[4];
    const float* w_c = (const float*)d_in[5];
    const float* v = (const float*)d_in[6];
    const float* b_attn = (const float*)d_in[7];

    float* out = (float*)d_out;
    float* ws = (float*)d_ws;
    float* Wh = ws + WH_OFF;
    float* Ws = ws + WS_OFF;
    float* Acov = ws + ACOV_OFF;

    const int nb_gemm = (B_ * S_) / ROWS + (BT_) / ROWS;  // 200 + 50
    k_gemm<<<nb_gemm, 256, 0, stream>>>(dec, enc, W_h, W_s, Wh, Ws);
    k_prelim<<<BT_, 256, 0, stream>>>(Wh, Ws, v, b_attn, mask, Acov);
    k_cumsum<<<(B_ * S_ + 255) / 256, 256, 0, stream>>>(Acov, out);
    k_final<<<BT_, 256, 0, stream>>>(Wh, Ws, v, b_attn, w_c, Acov, mask, enc, out);
}

// Round 3
// 195.784 us; speedup vs baseline: 1.2998x; 1.2998x over previous
//
#include <hip/hip_runtime.h>
#include <math.h>

#define B_ 8
#define T_ 100
#define S_ 400
#define H_ 256
#define BT_ (B_ * T_)
#define MAXL 30.0f

#define CTX_OFF 0
#define AF_OFF (BT_ * H_)
#define LOSS_OFF (BT_ * H_ + BT_ * S_)

// ws layout (floats)
#define WH_OFF 0
#define WS_OFF (B_ * S_ * H_)            // 819200
#define ACOV_OFF (WS_OFF + BT_ * H_)     // 1024000; size BT_*S_ = 320000

__device__ __forceinline__ float fast_tanh(float x) {
    // 1 - 2/(e^{2x}+1): saturates correctly for |x| large, ~1e-6 abs err
    float e = __expf(2.0f * x);
    return 1.0f - 2.0f * __builtin_amdgcn_rcpf(e + 1.0f);
}

__device__ __forceinline__ float wave_sum(float p) {
#pragma unroll
    for (int off = 32; off; off >>= 1) p += __shfl_xor(p, off, 64);
    return p;
}

__device__ __forceinline__ float wave_max(float p) {
#pragma unroll
    for (int off = 32; off; off >>= 1) p = fmaxf(p, __shfl_xor(p, off, 64));
    return p;
}

// 16-lane group reduce (4 stages, covers 4 s-values per wave simultaneously)
__device__ __forceinline__ float group16_sum(float p) {
    p += __shfl_xor(p, 1, 64);
    p += __shfl_xor(p, 2, 64);
    p += __shfl_xor(p, 4, 64);
    p += __shfl_xor(p, 8, 64);
    return p;
}

// dot of tanh(wv + bse) with vv over 4 elements
__device__ __forceinline__ float tanh_dot4(float4 wv, float4 bse, float4 vv) {
    return fast_tanh(wv.x + bse.x) * vv.x + fast_tanh(wv.y + bse.y) * vv.y +
           fast_tanh(wv.z + bse.z) * vv.z + fast_tanh(wv.w + bse.w) * vv.w;
}
__device__ __forceinline__ float tanh_dot4c(float4 wv, float4 bse, float c,
                                            float4 wc, float4 vv) {
    return fast_tanh(wv.x + bse.x + c * wc.x) * vv.x +
           fast_tanh(wv.y + bse.y + c * wc.y) * vv.y +
           fast_tanh(wv.z + bse.z + c * wc.z) * vv.z +
           fast_tanh(wv.w + bse.w + c * wc.w) * vv.w;
}

// ---------------- K1: Wh = enc @ W_h, Ws = dec @ W_s (row-block GEMM) --------
#define ROWS 16
__global__ __launch_bounds__(256) void k_gemm(
    const float* __restrict__ dec, const float* __restrict__ enc,
    const float* __restrict__ W_h, const float* __restrict__ W_s,
    float* __restrict__ Wh, float* __restrict__ Ws) {
    __shared__ float in_t[H_][ROWS];  // transposed: in_t[h][r]
    const int tid = threadIdx.x;
    const int blk = blockIdx.x;
    const int NB_ENC = (B_ * S_) / ROWS;  // 200

    const float* in;
    const float* W;
    float* out;
    int r0;
    if (blk < NB_ENC) {
        in = enc; W = W_h; out = Wh; r0 = blk * ROWS;
    } else {
        in = dec; W = W_s; out = Ws; r0 = (blk - NB_ENC) * ROWS;
    }

#pragma unroll
    for (int r = 0; r < ROWS; ++r)
        in_t[tid][r] = in[(size_t)(r0 + r) * H_ + tid];
    __syncthreads();

    float acc[ROWS];
#pragma unroll
    for (int r = 0; r < ROWS; ++r) acc[r] = 0.f;

    const float* Wp = W + tid;
    for (int h = 0; h < H_; ++h) {
        float w = Wp[(size_t)h * H_];
        const float4* ip = reinterpret_cast<const float4*>(&in_t[h][0]);
        float4 i0 = ip[0], i1 = ip[1], i2 = ip[2], i3 = ip[3];
        acc[0] += i0.x * w;  acc[1] += i0.y * w;  acc[2] += i0.z * w;  acc[3] += i0.w * w;
        acc[4] += i1.x * w;  acc[5] += i1.y * w;  acc[6] += i1.z * w;  acc[7] += i1.w * w;
        acc[8] += i2.x * w;  acc[9] += i2.y * w;  acc[10] += i2.z * w; acc[11] += i2.w * w;
        acc[12] += i3.x * w; acc[13] += i3.y * w; acc[14] += i3.z * w; acc[15] += i3.w * w;
    }
#pragma unroll
    for (int r = 0; r < ROWS; ++r)
        out[(size_t)(r0 + r) * H_ + tid] = acc[r];
}

// ---------------- K2: prelim logits + softmax -> A_prelim --------------------
__global__ __launch_bounds__(256) void k_prelim(
    const float* __restrict__ Wh, const float* __restrict__ Ws,
    const float* __restrict__ v, const float* __restrict__ b_attn,
    const unsigned char* __restrict__ mask,
    float* __restrict__ A) {
    __shared__ float e_lds[S_];
    __shared__ float red[8];
    const int bt = blockIdx.x;
    const int b = bt / T_;
    const int tid = threadIdx.x;
    const int lane = tid & 63;
    const int wid = tid >> 6;
    const int l = tid & 15;     // h-chunk within group (16 floats each)
    const int g = tid >> 4;     // group id 0..15

    // per-lane 16-element slices at h0 = l*16
    const float4* WsP = reinterpret_cast<const float4*>(Ws + (size_t)bt * H_ + l * 16);
    const float4* baP = reinterpret_cast<const float4*>(b_attn + l * 16);
    const float4* vP = reinterpret_cast<const float4*>(v + l * 16);
    float4 b0 = WsP[0], b1 = WsP[1], b2 = WsP[2], b3 = WsP[3];
    float4 a0 = baP[0], a1 = baP[1], a2 = baP[2], a3 = baP[3];
    b0.x += a0.x; b0.y += a0.y; b0.z += a0.z; b0.w += a0.w;
    b1.x += a1.x; b1.y += a1.y; b1.z += a1.z; b1.w += a1.w;
    b2.x += a2.x; b2.y += a2.y; b2.z += a2.z; b2.w += a2.w;
    b3.x += a3.x; b3.y += a3.y; b3.z += a3.z; b3.w += a3.w;
    const float4 v0 = vP[0], v1 = vP[1], v2 = vP[2], v3 = vP[3];

    const float* WhB = Wh + (size_t)b * S_ * H_;
    const unsigned char* mb = mask + (size_t)b * S_;

    for (int s = g; s < S_; s += 16) {
        const float4* wp = reinterpret_cast<const float4*>(WhB + (size_t)s * H_ + l * 16);
        float4 w0 = wp[0], w1 = wp[1], w2 = wp[2], w3 = wp[3];
        float p = tanh_dot4(w0, b0, v0) + tanh_dot4(w1, b1, v1) +
                  tanh_dot4(w2, b2, v2) + tanh_dot4(w3, b3, v3);
        p = group16_sum(p);
        if (l == 0) {
            float e = fminf(fmaxf(p, -MAXL), MAXL);
            if (mb[s]) e = -INFINITY;
            e_lds[s] = e;
        }
    }
    __syncthreads();

    // softmax over S_
    float mx = -INFINITY;
    for (int s = tid; s < S_; s += 256) mx = fmaxf(mx, e_lds[s]);
    mx = wave_max(mx);
    if (lane == 0) red[wid] = mx;
    __syncthreads();
    mx = fmaxf(fmaxf(red[0], red[1]), fmaxf(red[2], red[3]));

    float sum = 0.f;
    for (int s = tid; s < S_; s += 256) {
        float p = __expf(e_lds[s] - mx);
        e_lds[s] = p;
        sum += p;
    }
    sum = wave_sum(sum);
    if (lane == 0) red[4 + wid] = sum;
    __syncthreads();
    sum = (red[4] + red[5]) + (red[6] + red[7]);
    float inv = __builtin_amdgcn_rcpf(sum);

    float* Ar = A + (size_t)bt * S_;
    for (int s = tid; s < S_; s += 256) Ar[s] = e_lds[s] * inv;
}

// ---------------- K3: in-place shifted cumsum over t; zero loss --------------
__global__ __launch_bounds__(256) void k_cumsum(float* __restrict__ A,
                                                float* __restrict__ out) {
    const int idx = blockIdx.x * 256 + threadIdx.x;  // b*S + s
    if (idx == 0) out[LOSS_OFF] = 0.f;
    if (idx >= B_ * S_) return;
    const int b = idx / S_;
    const int s = idx - b * S_;
    float* col = A + (size_t)b * T_ * S_ + s;
    float run = 0.f;
#pragma unroll 10
    for (int t = 0; t < T_; ++t) {
        float a = col[(size_t)t * S_];
        col[(size_t)t * S_] = run;  // cov_shifted
        run += a;
    }
}

// ---------------- K4: final logits + softmax + context + loss ----------------
__global__ __launch_bounds__(256) void k_final(
    const float* __restrict__ Wh, const float* __restrict__ Ws,
    const float* __restrict__ v, const float* __restrict__ b_attn,
    const float* __restrict__ w_c, const float* __restrict__ cov,
    const unsigned char* __restrict__ mask,
    const float* __restrict__ enc,
    float* __restrict__ out) {
    __shared__ float e_lds[S_];
    __shared__ float cov_lds[S_];
    __shared__ float red[8];
    const int bt = blockIdx.x;
    const int b = bt / T_;
    const int tid = threadIdx.x;
    const int lane = tid & 63;
    const int wid = tid >> 6;
    const int l = tid & 15;
    const int g = tid >> 4;

    const float4* WsP = reinterpret_cast<const float4*>(Ws + (size_t)bt * H_ + l * 16);
    const float4* baP = reinterpret_cast<const float4*>(b_attn + l * 16);
    const float4* vP = reinterpret_cast<const float4*>(v + l * 16);
    const float4* wcP = reinterpret_cast<const float4*>(w_c + l * 16);
    float4 b0 = WsP[0], b1 = WsP[1], b2 = WsP[2], b3 = WsP[3];
    float4 a0 = baP[0], a1 = baP[1], a2 = baP[2], a3 = baP[3];
    b0.x += a0.x; b0.y += a0.y; b0.z += a0.z; b0.w += a0.w;
    b1.x += a1.x; b1.y += a1.y; b1.z += a1.z; b1.w += a1.w;
    b2.x += a2.x; b2.y += a2.y; b2.z += a2.z; b2.w += a2.w;
    b3.x += a3.x; b3.y += a3.y; b3.z += a3.z; b3.w += a3.w;
    const float4 v0 = vP[0], v1 = vP[1], v2 = vP[2], v3 = vP[3];
    const float4 c0 = wcP[0], c1 = wcP[1], c2 = wcP[2], c3 = wcP[3];

    const float* covR = cov + (size_t)bt * S_;
    for (int s = tid; s < S_; s += 256) cov_lds[s] = covR[s];
    __syncthreads();

    const float* WhB = Wh + (size_t)b * S_ * H_;
    const unsigned char* mb = mask + (size_t)b * S_;

    for (int s = g; s < S_; s += 16) {
        const float c = cov_lds[s];
        const float4* wp = reinterpret_cast<const float4*>(WhB + (size_t)s * H_ + l * 16);
        float4 w0 = wp[0], w1 = wp[1], w2 = wp[2], w3 = wp[3];
        float p = tanh_dot4c(w0, b0, c, c0, v0) + tanh_dot4c(w1, b1, c, c1, v1) +
                  tanh_dot4c(w2, b2, c, c2, v2) + tanh_dot4c(w3, b3, c, c3, v3);
        p = group16_sum(p);
        if (l == 0) {
            float e = fminf(fmaxf(p, -MAXL), MAXL);
            if (mb[s]) e = -INFINITY;
            e_lds[s] = e;
        }
    }
    __syncthreads();

    float mx = -INFINITY;
    for (int s = tid; s < S_; s += 256) mx = fmaxf(mx, e_lds[s]);
    mx = wave_max(mx);
    if (lane == 0) red[wid] = mx;
    __syncthreads();
    mx = fmaxf(fmaxf(red[0], red[1]), fmaxf(red[2], red[3]));

    float sum = 0.f;
    for (int s = tid; s < S_; s += 256) {
        float p = __expf(e_lds[s] - mx);
        e_lds[s] = p;
        sum += p;
    }
    sum = wave_sum(sum);
    if (lane == 0) red[4 + wid] = sum;
    __syncthreads();
    sum = (red[4] + red[5]) + (red[6] + red[7]);
    const float inv = __builtin_amdgcn_rcpf(sum);

    float* Ar = out + AF_OFF + (size_t)bt * S_;
    for (int s = tid; s < S_; s += 256) {
        float a = e_lds[s] * inv;
        e_lds[s] = a;
        Ar[s] = a;
    }
    __syncthreads();

    // context[b,t,h] = sum_s A[s] * enc[b,s,h]; thread = h
    const float* eb = enc + (size_t)b * S_ * H_ + tid;
    float cacc = 0.f;
#pragma unroll 8
    for (int s = 0; s < S_; ++s) cacc += e_lds[s] * eb[(size_t)s * H_];
    out[(size_t)bt * H_ + tid] = cacc;

    // cov loss partial
    float lp = 0.f;
    for (int s = tid; s < S_; s += 256) lp += fminf(e_lds[s], cov_lds[s]);
    lp = wave_sum(lp);
    if (lane == 0) red[wid] = lp;
    __syncthreads();
    if (tid == 0) {
        float tot = (red[0] + red[1]) + (red[2] + red[3]);
        atomicAdd(out + LOSS_OFF, tot * (1.0f / (B_ * T_)));
    }
}

extern "C" void kernel_launch(void* const* d_in, const int* in_sizes, int n_in,
                              void* d_out, int out_size, void* d_ws, size_t ws_size,
                              hipStream_t stream) {
    const float* dec = (const float*)d_in[0];
    const float* enc = (const float*)d_in[1];
    const unsigned char* mask = (const unsigned char*)d_in[2];
    const float* W_h = (const float*)d_in[3];
    const float* W_s = (const float*)d_in[4];
    const float* w_c = (const float*)d_in[5];
    const float* v = (const float*)d_in[6];
    const float* b_attn = (const float*)d_in[7];

    float* out = (float*)d_out;
    float* ws = (float*)d_ws;
    float* Wh = ws + WH_OFF;
    float* Ws = ws + WS_OFF;
    float* Acov = ws + ACOV_OFF;

    const int nb_gemm = (B_ * S_) / ROWS + (BT_) / ROWS;  // 200 + 50
    k_gemm<<<nb_gemm, 256, 0, stream>>>(dec, enc, W_h, W_s, Wh, Ws);
    k_prelim<<<BT_, 256, 0, stream>>>(Wh, Ws, v, b_attn, mask, Acov);
    k_cumsum<<<(B_ * S_ + 255) / 256, 256, 0, stream>>>(Acov, out);
    k_final<<<BT_, 256, 0, stream>>>(Wh, Ws, v, b_attn, w_c, Acov, mask, enc, out);
}

// Round 4
// 181.777 us; speedup vs baseline: 1.3999x; 1.0771x over previous
//
#include <hip/hip_runtime.h>
#include <math.h>

#define B_ 8
#define T_ 100
#define S_ 400
#define H_ 256
#define BT_ (B_ * T_)
#define MAXL 30.0f

#define AF_OFF (BT_ * H_)
#define LOSS_OFF (BT_ * H_ + BT_ * S_)

// ws layout (floats)
#define WH_OFF 0
#define WS_OFF (B_ * S_ * H_)            // 819200
#define ACOV_OFF (WS_OFF + BT_ * H_)     // 1024000; size BT_*S_ = 320000

__device__ __forceinline__ float fast_tanh(float x) {
    float e = __expf(2.0f * x);
    return 1.0f - 2.0f * __builtin_amdgcn_rcpf(e + 1.0f);
}

__device__ __forceinline__ float wave_sum(float p) {
#pragma unroll
    for (int off = 32; off; off >>= 1) p += __shfl_xor(p, off, 64);
    return p;
}

__device__ __forceinline__ float wave_max(float p) {
#pragma unroll
    for (int off = 32; off; off >>= 1) p = fmaxf(p, __shfl_xor(p, off, 64));
    return p;
}

// 16-lane group reduce (4 stages; one wave covers 4 s-values at once)
__device__ __forceinline__ float group16_sum(float p) {
    p += __shfl_xor(p, 1, 64);
    p += __shfl_xor(p, 2, 64);
    p += __shfl_xor(p, 4, 64);
    p += __shfl_xor(p, 8, 64);
    return p;
}

__device__ __forceinline__ float tanh_dot4(float4 wv, float4 bse, float4 vv) {
    return fast_tanh(wv.x + bse.x) * vv.x + fast_tanh(wv.y + bse.y) * vv.y +
           fast_tanh(wv.z + bse.z) * vv.z + fast_tanh(wv.w + bse.w) * vv.w;
}
__device__ __forceinline__ float tanh_dot4c(float4 wv, float4 bse, float c,
                                            float4 wc, float4 vv) {
    return fast_tanh(wv.x + bse.x + c * wc.x) * vv.x +
           fast_tanh(wv.y + bse.y + c * wc.y) * vv.y +
           fast_tanh(wv.z + bse.z + c * wc.z) * vv.z +
           fast_tanh(wv.w + bse.w + c * wc.w) * vv.w;
}

// ---------------- K1: Wh = enc @ W_h, Ws = dec @ W_s --------------------------
// ROWS=4 rows per block -> 1000 blocks (~4 waves/SIMD). Input row values are
// block-uniform -> compiler emits scalar s_loads; no LDS, no barriers.
#define ROWS 4
__global__ __launch_bounds__(256) void k_gemm(
    const float* __restrict__ dec, const float* __restrict__ enc,
    const float* __restrict__ W_h, const float* __restrict__ W_s,
    float* __restrict__ Wh, float* __restrict__ Ws) {
    const int tid = threadIdx.x;
    const int blk = blockIdx.x;
    const int NB_ENC = (B_ * S_) / ROWS;  // 800

    const float* in;
    const float* W;
    float* out;
    int r0;
    if (blk < NB_ENC) {
        in = enc; W = W_h; out = Wh; r0 = blk * ROWS;
    } else {
        in = dec; W = W_s; out = Ws; r0 = (blk - NB_ENC) * ROWS;
    }

    const float* i0 = in + (size_t)r0 * H_;
    const float* i1 = i0 + H_;
    const float* i2 = i1 + H_;
    const float* i3 = i2 + H_;
    const float* Wp = W + tid;

    float a0 = 0.f, a1 = 0.f, a2 = 0.f, a3 = 0.f;
#pragma unroll 8
    for (int h = 0; h < H_; ++h) {
        float w = Wp[(size_t)h * H_];
        a0 = fmaf(i0[h], w, a0);
        a1 = fmaf(i1[h], w, a1);
        a2 = fmaf(i2[h], w, a2);
        a3 = fmaf(i3[h], w, a3);
    }
    out[(size_t)(r0 + 0) * H_ + tid] = a0;
    out[(size_t)(r0 + 1) * H_ + tid] = a1;
    out[(size_t)(r0 + 2) * H_ + tid] = a2;
    out[(size_t)(r0 + 3) * H_ + tid] = a3;
}

// ---------------- K2: prelim logits + softmax -> A_prelim --------------------
// 512 threads, XCD-swizzled: b = blk&7 so each XCD's L2 holds one batch.
__global__ __launch_bounds__(512) void k_prelim(
    const float* __restrict__ Wh, const float* __restrict__ Ws,
    const float* __restrict__ v, const float* __restrict__ b_attn,
    const unsigned char* __restrict__ mask,
    float* __restrict__ A) {
    __shared__ float e_lds[S_];
    __shared__ float red[16];
    const int blk = blockIdx.x;
    const int b = blk & 7;
    const int t = blk >> 3;
    const int bt = b * T_ + t;
    const int tid = threadIdx.x;
    const int lane = tid & 63;
    const int wid = tid >> 6;   // 0..7
    const int l = tid & 15;     // h-chunk (16 floats)
    const int g = tid >> 4;     // group id 0..31

    const float4* WsP = reinterpret_cast<const float4*>(Ws + (size_t)bt * H_ + l * 16);
    const float4* baP = reinterpret_cast<const float4*>(b_attn + l * 16);
    const float4* vP = reinterpret_cast<const float4*>(v + l * 16);
    float4 b0 = WsP[0], b1 = WsP[1], b2 = WsP[2], b3 = WsP[3];
    float4 a0 = baP[0], a1 = baP[1], a2 = baP[2], a3 = baP[3];
    b0.x += a0.x; b0.y += a0.y; b0.z += a0.z; b0.w += a0.w;
    b1.x += a1.x; b1.y += a1.y; b1.z += a1.z; b1.w += a1.w;
    b2.x += a2.x; b2.y += a2.y; b2.z += a2.z; b2.w += a2.w;
    b3.x += a3.x; b3.y += a3.y; b3.z += a3.z; b3.w += a3.w;
    const float4 v0 = vP[0], v1 = vP[1], v2 = vP[2], v3 = vP[3];

    const float* WhB = Wh + (size_t)b * S_ * H_;
    const unsigned char* mb = mask + (size_t)b * S_;

    for (int s = g; s < S_; s += 32) {
        const float4* wp = reinterpret_cast<const float4*>(WhB + (size_t)s * H_ + l * 16);
        float4 w0 = wp[0], w1 = wp[1], w2 = wp[2], w3 = wp[3];
        float p = tanh_dot4(w0, b0, v0) + tanh_dot4(w1, b1, v1) +
                  tanh_dot4(w2, b2, v2) + tanh_dot4(w3, b3, v3);
        p = group16_sum(p);
        if (l == 0) {
            float e = fminf(fmaxf(p, -MAXL), MAXL);
            if (mb[s]) e = -INFINITY;
            e_lds[s] = e;
        }
    }
    __syncthreads();

    // softmax: one element per thread (S_=400 < 512)
    float mx = (tid < S_) ? e_lds[tid] : -INFINITY;
    mx = wave_max(mx);
    if (lane == 0) red[wid] = mx;
    __syncthreads();
    mx = fmaxf(fmaxf(fmaxf(red[0], red[1]), fmaxf(red[2], red[3])),
               fmaxf(fmaxf(red[4], red[5]), fmaxf(red[6], red[7])));

    float p = (tid < S_) ? __expf(e_lds[tid] - mx) : 0.f;
    float sum = wave_sum(p);
    if (lane == 0) red[8 + wid] = sum;
    __syncthreads();
    sum = ((red[8] + red[9]) + (red[10] + red[11])) +
          ((red[12] + red[13]) + (red[14] + red[15]));
    const float inv = __builtin_amdgcn_rcpf(sum);

    if (tid < S_) A[(size_t)bt * S_ + tid] = p * inv;
}

// ---------------- K3: in-place shifted cumsum over t; zero loss --------------
__global__ __launch_bounds__(256) void k_cumsum(float* __restrict__ A,
                                                float* __restrict__ out) {
    const int idx = blockIdx.x * 256 + threadIdx.x;  // b*S + s
    if (idx == 0) out[LOSS_OFF] = 0.f;
    if (idx >= B_ * S_) return;
    const int b = idx / S_;
    const int s = idx - b * S_;
    float* col = A + (size_t)b * T_ * S_ + s;
    float run = 0.f;
#pragma unroll 10
    for (int t = 0; t < T_; ++t) {
        float a = col[(size_t)t * S_];
        col[(size_t)t * S_] = run;  // cov_shifted
        run += a;
    }
}

// ---------------- K4: final logits + softmax + context + loss ----------------
__global__ __launch_bounds__(512) void k_final(
    const float* __restrict__ Wh, const float* __restrict__ Ws,
    const float* __restrict__ v, const float* __restrict__ b_attn,
    const float* __restrict__ w_c, const float* __restrict__ cov,
    const unsigned char* __restrict__ mask,
    const float* __restrict__ enc,
    float* __restrict__ out) {
    __shared__ float e_lds[S_];
    __shared__ float cov_lds[S_];
    __shared__ float ctx_part[H_];
    __shared__ float red[16];
    const int blk = blockIdx.x;
    const int b = blk & 7;
    const int t = blk >> 3;
    const int bt = b * T_ + t;
    const int tid = threadIdx.x;
    const int lane = tid & 63;
    const int wid = tid >> 6;
    const int l = tid & 15;
    const int g = tid >> 4;

    const float4* WsP = reinterpret_cast<const float4*>(Ws + (size_t)bt * H_ + l * 16);
    const float4* baP = reinterpret_cast<const float4*>(b_attn + l * 16);
    const float4* vP = reinterpret_cast<const float4*>(v + l * 16);
    const float4* wcP = reinterpret_cast<const float4*>(w_c + l * 16);
    float4 b0 = WsP[0], b1 = WsP[1], b2 = WsP[2], b3 = WsP[3];
    float4 a0 = baP[0], a1 = baP[1], a2 = baP[2], a3 = baP[3];
    b0.x += a0.x; b0.y += a0.y; b0.z += a0.z; b0.w += a0.w;
    b1.x += a1.x; b1.y += a1.y; b1.z += a1.z; b1.w += a1.w;
    b2.x += a2.x; b2.y += a2.y; b2.z += a2.z; b2.w += a2.w;
    b3.x += a3.x; b3.y += a3.y; b3.z += a3.z; b3.w += a3.w;
    const float4 v0 = vP[0], v1 = vP[1], v2 = vP[2], v3 = vP[3];
    const float4 c0 = wcP[0], c1 = wcP[1], c2 = wcP[2], c3 = wcP[3];

    float covreg = 0.f;
    if (tid < S_) {
        covreg = cov[(size_t)bt * S_ + tid];
        cov_lds[tid] = covreg;
    }
    __syncthreads();

    const float* WhB = Wh + (size_t)b * S_ * H_;
    const unsigned char* mb = mask + (size_t)b * S_;

    for (int s = g; s < S_; s += 32) {
        const float c = cov_lds[s];
        const float4* wp = reinterpret_cast<const float4*>(WhB + (size_t)s * H_ + l * 16);
        float4 w0 = wp[0], w1 = wp[1], w2 = wp[2], w3 = wp[3];
        float p = tanh_dot4c(w0, b0, c, c0, v0) + tanh_dot4c(w1, b1, c, c1, v1) +
                  tanh_dot4c(w2, b2, c, c2, v2) + tanh_dot4c(w3, b3, c, c3, v3);
        p = group16_sum(p);
        if (l == 0) {
            float e = fminf(fmaxf(p, -MAXL), MAXL);
            if (mb[s]) e = -INFINITY;
            e_lds[s] = e;
        }
    }
    __syncthreads();

    float mx = (tid < S_) ? e_lds[tid] : -INFINITY;
    mx = wave_max(mx);
    if (lane == 0) red[wid] = mx;
    __syncthreads();
    mx = fmaxf(fmaxf(fmaxf(red[0], red[1]), fmaxf(red[2], red[3])),
               fmaxf(fmaxf(red[4], red[5]), fmaxf(red[6], red[7])));

    float p = (tid < S_) ? __expf(e_lds[tid] - mx) : 0.f;
    float sum = wave_sum(p);
    if (lane == 0) red[8 + wid] = sum;
    __syncthreads();
    sum = ((red[8] + red[9]) + (red[10] + red[11])) +
          ((red[12] + red[13]) + (red[14] + red[15]));
    const float inv = __builtin_amdgcn_rcpf(sum);

    const float a = (tid < S_) ? p * inv : 0.f;

    // cov-loss partial entirely in registers (a, covreg) — reuse red[0..7]
    float lp = (tid < S_) ? fminf(a, covreg) : 0.f;
    lp = wave_sum(lp);
    if (lane == 0) red[wid] = lp;

    if (tid < S_) {
        e_lds[tid] = a;
        out[AF_OFF + (size_t)bt * S_ + tid] = a;
    }
    __syncthreads();

    if (tid == 0) {
        float tot = ((red[0] + red[1]) + (red[2] + red[3])) +
                    ((red[4] + red[5]) + (red[6] + red[7]));
        atomicAdd(out + LOSS_OFF, tot * (1.0f / (B_ * T_)));
    }

    // context[b,t,h] = sum_s A[s]*enc[b,s,h]; 2 threads per h, each half of s
    const int h = tid & (H_ - 1);
    const int half = tid >> 8;           // 0 or 1
    const int s0 = half * (S_ / 2);      // 0 or 200
    const float* eb = enc + ((size_t)b * S_ + s0) * H_ + h;
    float cacc = 0.f;
#pragma unroll 8
    for (int j = 0; j < S_ / 2; ++j) cacc += e_lds[s0 + j] * eb[(size_t)j * H_];
    if (half == 0) ctx_part[h] = cacc;
    __syncthreads();
    if (half == 1) out[(size_t)bt * H_ + h] = ctx_part[h] + cacc;
}

extern "C" void kernel_launch(void* const* d_in, const int* in_sizes, int n_in,
                              void* d_out, int out_size, void* d_ws, size_t ws_size,
                              hipStream_t stream) {
    const float* dec = (const float*)d_in[0];
    const float* enc = (const float*)d_in[1];
    const unsigned char* mask = (const unsigned char*)d_in[2];
    const float* W_h = (const float*)d_in[3];
    const float* W_s = (const float*)d_in[4];
    const float* w_c = (const float*)d_in[5];
    const float* v = (const float*)d_in[6];
    const float* b_attn = (const float*)d_in[7];

    float* out = (float*)d_out;
    float* ws = (float*)d_ws;
    float* Wh = ws + WH_OFF;
    float* Ws = ws + WS_OFF;
    float* Acov = ws + ACOV_OFF;

    const int nb_gemm = (B_ * S_) / ROWS + BT_ / ROWS;  // 800 + 200
    k_gemm<<<nb_gemm, 256, 0, stream>>>(dec, enc, W_h, W_s, Wh, Ws);
    k_prelim<<<BT_, 512, 0, stream>>>(Wh, Ws, v, b_attn, mask, Acov);
    k_cumsum<<<(B_ * S_ + 255) / 256, 256, 0, stream>>>(Acov, out);
    k_final<<<BT_, 512, 0, stream>>>(Wh, Ws, v, b_attn, w_c, Acov, mask, enc, out);
}

// Round 5
// 179.676 us; speedup vs baseline: 1.4163x; 1.0117x over previous
//
#include <hip/hip_runtime.h>
#include <math.h>

#define B_ 8
#define T_ 100
#define S_ 400
#define H_ 256
#define BT_ (B_ * T_)
#define MAXL 30.0f

#define AF_OFF (BT_ * H_)
#define LOSS_OFF (BT_ * H_ + BT_ * S_)

// ws layout (floats)
#define WH_OFF 0
#define WS_OFF (B_ * S_ * H_)            // 819200
#define ACOV_OFF (WS_OFF + BT_ * H_)     // 1024000; size BT_*S_ = 320000

__device__ __forceinline__ float fast_tanh(float x) {
    float e = __expf(2.0f * x);
    return 1.0f - 2.0f * __builtin_amdgcn_rcpf(e + 1.0f);
}

__device__ __forceinline__ float wave_sum(float p) {
#pragma unroll
    for (int off = 32; off; off >>= 1) p += __shfl_xor(p, off, 64);
    return p;
}

__device__ __forceinline__ float wave_max(float p) {
#pragma unroll
    for (int off = 32; off; off >>= 1) p = fmaxf(p, __shfl_xor(p, off, 64));
    return p;
}

// 16-lane group reduce (4 stages; one wave covers 4 s-values at once)
__device__ __forceinline__ float group16_sum(float p) {
    p += __shfl_xor(p, 1, 64);
    p += __shfl_xor(p, 2, 64);
    p += __shfl_xor(p, 4, 64);
    p += __shfl_xor(p, 8, 64);
    return p;
}

__device__ __forceinline__ float tanh_dot4(float4 wv, float4 bse, float4 vv) {
    return fast_tanh(wv.x + bse.x) * vv.x + fast_tanh(wv.y + bse.y) * vv.y +
           fast_tanh(wv.z + bse.z) * vv.z + fast_tanh(wv.w + bse.w) * vv.w;
}
__device__ __forceinline__ float tanh_dot4c(float4 wv, float4 bse, float c,
                                            float4 wc, float4 vv) {
    return fast_tanh(wv.x + bse.x + c * wc.x) * vv.x +
           fast_tanh(wv.y + bse.y + c * wc.y) * vv.y +
           fast_tanh(wv.z + bse.z + c * wc.z) * vv.z +
           fast_tanh(wv.w + bse.w + c * wc.w) * vv.w;
}

// ---------------- K1: Wh = enc @ W_h, Ws = dec @ W_s (+b_attn) ----------------
// ROWS=4 rows per block -> 1000 blocks. Input row values are block-uniform ->
// scalar s_loads; no LDS, no barriers. b_attn folded into Ws output.
#define ROWS 4
__global__ __launch_bounds__(256) void k_gemm(
    const float* __restrict__ dec, const float* __restrict__ enc,
    const float* __restrict__ W_h, const float* __restrict__ W_s,
    const float* __restrict__ b_attn,
    float* __restrict__ Wh, float* __restrict__ Ws) {
    const int tid = threadIdx.x;
    const int blk = blockIdx.x;
    const int NB_ENC = (B_ * S_) / ROWS;  // 800

    const float* in;
    const float* W;
    float* out;
    int r0;
    float bias = 0.f;
    if (blk < NB_ENC) {
        in = enc; W = W_h; out = Wh; r0 = blk * ROWS;
    } else {
        in = dec; W = W_s; out = Ws; r0 = (blk - NB_ENC) * ROWS;
        bias = b_attn[tid];
    }

    const float* i0 = in + (size_t)r0 * H_;
    const float* i1 = i0 + H_;
    const float* i2 = i1 + H_;
    const float* i3 = i2 + H_;
    const float* Wp = W + tid;

    float a0 = bias, a1 = bias, a2 = bias, a3 = bias;
#pragma unroll 8
    for (int h = 0; h < H_; ++h) {
        float w = Wp[(size_t)h * H_];
        a0 = fmaf(i0[h], w, a0);
        a1 = fmaf(i1[h], w, a1);
        a2 = fmaf(i2[h], w, a2);
        a3 = fmaf(i3[h], w, a3);
    }
    out[(size_t)(r0 + 0) * H_ + tid] = a0;
    out[(size_t)(r0 + 1) * H_ + tid] = a1;
    out[(size_t)(r0 + 2) * H_ + tid] = a2;
    out[(size_t)(r0 + 3) * H_ + tid] = a3;
}

// ---------------- K2: prelim logits + softmax -> A_prelim --------------------
// 512 threads; XCD-swizzled (b = blk&7). launch_bounds(512,3): allow ~170 VGPR
// so the 32 loop-invariant floats (base, v) stay register-resident.
__global__ __launch_bounds__(512, 3) void k_prelim(
    const float* __restrict__ Wh, const float* __restrict__ Ws,
    const float* __restrict__ v,
    const unsigned char* __restrict__ mask,
    float* __restrict__ A) {
    __shared__ float e_lds[S_];
    __shared__ float red[16];
    const int blk = blockIdx.x;
    const int b = blk & 7;
    const int t = blk >> 3;
    const int bt = b * T_ + t;
    const int tid = threadIdx.x;
    const int lane = tid & 63;
    const int wid = tid >> 6;   // 0..7
    const int l = tid & 15;     // h-chunk (16 floats)
    const int g = tid >> 4;     // group id 0..31

    const float4* WsP = reinterpret_cast<const float4*>(Ws + (size_t)bt * H_ + l * 16);
    const float4* vP = reinterpret_cast<const float4*>(v + l * 16);
    const float4 b0 = WsP[0], b1 = WsP[1], b2 = WsP[2], b3 = WsP[3];
    const float4 v0 = vP[0], v1 = vP[1], v2 = vP[2], v3 = vP[3];

    const float* WhB = Wh + (size_t)b * S_ * H_;
    const unsigned char* mb = mask + (size_t)b * S_;

    for (int s = g; s < S_; s += 32) {
        const float4* wp = reinterpret_cast<const float4*>(WhB + (size_t)s * H_ + l * 16);
        float4 w0 = wp[0], w1 = wp[1], w2 = wp[2], w3 = wp[3];
        float p = tanh_dot4(w0, b0, v0) + tanh_dot4(w1, b1, v1) +
                  tanh_dot4(w2, b2, v2) + tanh_dot4(w3, b3, v3);
        p = group16_sum(p);
        if (l == 0) {
            float e = fminf(fmaxf(p, -MAXL), MAXL);
            if (mb[s]) e = -INFINITY;
            e_lds[s] = e;
        }
    }
    __syncthreads();

    // softmax: one element per thread (S_=400 < 512)
    float mx = (tid < S_) ? e_lds[tid] : -INFINITY;
    mx = wave_max(mx);
    if (lane == 0) red[wid] = mx;
    __syncthreads();
    mx = fmaxf(fmaxf(fmaxf(red[0], red[1]), fmaxf(red[2], red[3])),
               fmaxf(fmaxf(red[4], red[5]), fmaxf(red[6], red[7])));

    float p = (tid < S_) ? __expf(e_lds[tid] - mx) : 0.f;
    float sum = wave_sum(p);
    if (lane == 0) red[8 + wid] = sum;
    __syncthreads();
    sum = ((red[8] + red[9]) + (red[10] + red[11])) +
          ((red[12] + red[13]) + (red[14] + red[15]));
    const float inv = __builtin_amdgcn_rcpf(sum);

    if (tid < S_) A[(size_t)bt * S_ + tid] = p * inv;
}

// ---------------- K3: in-place shifted cumsum over t; zero loss --------------
__global__ __launch_bounds__(256) void k_cumsum(float* __restrict__ A,
                                                float* __restrict__ out) {
    const int idx = blockIdx.x * 256 + threadIdx.x;  // b*S + s
    if (idx == 0) out[LOSS_OFF] = 0.f;
    if (idx >= B_ * S_) return;
    const int b = idx / S_;
    const int s = idx - b * S_;
    float* col = A + (size_t)b * T_ * S_ + s;
    float run = 0.f;
#pragma unroll 10
    for (int t = 0; t < T_; ++t) {
        float a = col[(size_t)t * S_];
        col[(size_t)t * S_] = run;  // cov_shifted
        run += a;
    }
}

// ---------------- K4: final logits + softmax + context + loss ----------------
__global__ __launch_bounds__(512, 3) void k_final(
    const float* __restrict__ Wh, const float* __restrict__ Ws,
    const float* __restrict__ v,
    const float* __restrict__ w_c, const float* __restrict__ cov,
    const unsigned char* __restrict__ mask,
    const float* __restrict__ enc,
    float* __restrict__ out) {
    __shared__ float e_lds[S_];
    __shared__ float cov_lds[S_];
    __shared__ float ctx_part[H_];
    __shared__ float red[16];
    const int blk = blockIdx.x;
    const int b = blk & 7;
    const int t = blk >> 3;
    const int bt = b * T_ + t;
    const int tid = threadIdx.x;
    const int lane = tid & 63;
    const int wid = tid >> 6;
    const int l = tid & 15;
    const int g = tid >> 4;

    const float4* WsP = reinterpret_cast<const float4*>(Ws + (size_t)bt * H_ + l * 16);
    const float4* vP = reinterpret_cast<const float4*>(v + l * 16);
    const float4* wcP = reinterpret_cast<const float4*>(w_c + l * 16);
    const float4 b0 = WsP[0], b1 = WsP[1], b2 = WsP[2], b3 = WsP[3];
    const float4 v0 = vP[0], v1 = vP[1], v2 = vP[2], v3 = vP[3];
    const float4 c0 = wcP[0], c1 = wcP[1], c2 = wcP[2], c3 = wcP[3];

    float covreg = 0.f;
    if (tid < S_) {
        covreg = cov[(size_t)bt * S_ + tid];
        cov_lds[tid] = covreg;
    }
    __syncthreads();

    const float* WhB = Wh + (size_t)b * S_ * H_;
    const unsigned char* mb = mask + (size_t)b * S_;

    for (int s = g; s < S_; s += 32) {
        const float c = cov_lds[s];
        const float4* wp = reinterpret_cast<const float4*>(WhB + (size_t)s * H_ + l * 16);
        float4 w0 = wp[0], w1 = wp[1], w2 = wp[2], w3 = wp[3];
        float p = tanh_dot4c(w0, b0, c, c0, v0) + tanh_dot4c(w1, b1, c, c1, v1) +
                  tanh_dot4c(w2, b2, c, c2, v2) + tanh_dot4c(w3, b3, c, c3, v3);
        p = group16_sum(p);
        if (l == 0) {
            float e = fminf(fmaxf(p, -MAXL), MAXL);
            if (mb[s]) e = -INFINITY;
            e_lds[s] = e;
        }
    }
    __syncthreads();

    float mx = (tid < S_) ? e_lds[tid] : -INFINITY;
    mx = wave_max(mx);
    if (lane == 0) red[wid] = mx;
    __syncthreads();
    mx = fmaxf(fmaxf(fmaxf(red[0], red[1]), fmaxf(red[2], red[3])),
               fmaxf(fmaxf(red[4], red[5]), fmaxf(red[6], red[7])));

    float p = (tid < S_) ? __expf(e_lds[tid] - mx) : 0.f;
    float sum = wave_sum(p);
    if (lane == 0) red[8 + wid] = sum;
    __syncthreads();
    sum = ((red[8] + red[9]) + (red[10] + red[11])) +
          ((red[12] + red[13]) + (red[14] + red[15]));
    const float inv = __builtin_amdgcn_rcpf(sum);

    const float a = (tid < S_) ? p * inv : 0.f;

    // cov-loss partial entirely in registers — reuse red[0..7]
    float lp = (tid < S_) ? fminf(a, covreg) : 0.f;
    lp = wave_sum(lp);
    if (lane == 0) red[wid] = lp;

    if (tid < S_) {
        e_lds[tid] = a;
        out[AF_OFF + (size_t)bt * S_ + tid] = a;
    }
    __syncthreads();

    if (tid == 0) {
        float tot = ((red[0] + red[1]) + (red[2] + red[3])) +
                    ((red[4] + red[5]) + (red[6] + red[7]));
        atomicAdd(out + LOSS_OFF, tot * (1.0f / (B_ * T_)));
    }

    // context[b,t,h] = sum_s A[s]*enc[b,s,h]; 2 threads per h, each half of s
    const int h = tid & (H_ - 1);
    const int half = tid >> 8;           // 0 or 1
    const int s0 = half * (S_ / 2);      // 0 or 200
    const float* eb = enc + ((size_t)b * S_ + s0) * H_ + h;
    float cacc = 0.f;
#pragma unroll 8
    for (int j = 0; j < S_ / 2; ++j) cacc += e_lds[s0 + j] * eb[(size_t)j * H_];
    if (half == 0) ctx_part[h] = cacc;
    __syncthreads();
    if (half == 1) out[(size_t)bt * H_ + h] = ctx_part[h] + cacc;
}

extern "C" void kernel_launch(void* const* d_in, const int* in_sizes, int n_in,
                              void* d_out, int out_size, void* d_ws, size_t ws_size,
                              hipStream_t stream) {
    const float* dec = (const float*)d_in[0];
    const float* enc = (const float*)d_in[1];
    const unsigned char* mask = (const unsigned char*)d_in[2];
    const float* W_h = (const float*)d_in[3];
    const float* W_s = (const float*)d_in[4];
    const float* w_c = (const float*)d_in[5];
    const float* v = (const float*)d_in[6];
    const float* b_attn = (const float*)d_in[7];

    float* out = (float*)d_out;
    float* ws = (float*)d_ws;
    float* Wh = ws + WH_OFF;
    float* Ws = ws + WS_OFF;
    float* Acov = ws + ACOV_OFF;

    const int nb_gemm = (B_ * S_) / ROWS + BT_ / ROWS;  // 800 + 200
    k_gemm<<<nb_gemm, 256, 0, stream>>>(dec, enc, W_h, W_s, b_attn, Wh, Ws);
    k_prelim<<<BT_, 512, 0, stream>>>(Wh, Ws, v, mask, Acov);
    k_cumsum<<<(B_ * S_ + 255) / 256, 256, 0, stream>>>(Acov, out);
    k_final<<<BT_, 512, 0, stream>>>(Wh, Ws, v, w_c, Acov, mask, enc, out);
}